// Round 1
// baseline (180.270 us; speedup 1.0000x reference)
//
#include <hip/hip_runtime.h>

// Max-unpool 2x2 (stride 2, non-overlapping windows).
// x:     [N=32, C=64, H=64, W=64] fp32
// where: same shape, int32 in [0,4): pos = sy*2 + sx within the 2x2 window
// out:   [N, C, 2H=128, 2W=128] fp32; out[n,c,2h+sy,2w+sx] = (where==pos) ? x : 0
//
// Scatter layout: one thread per PAIR of consecutive input pixels along W.
// Loads float2/int2 (8B), stores two float4 (16B) -- one per output row.
// Every output element is written exactly once (windows don't overlap), so no
// zero-init pass is needed despite the 0xAA poison.

__global__ __launch_bounds__(256) void WhatWhereUnPooling2D_51522427683437_kernel(
    const float* __restrict__ x,
    const int* __restrict__ where,
    float* __restrict__ out,
    int n_pairs) {
    int tid = blockIdx.x * blockDim.x + threadIdx.x;
    if (tid >= n_pairs) return;

    // Input geometry: W=64 -> 32 pairs/row, H=64 rows, N*C=2048 planes.
    int w2  = tid & 31;        // pair index within row: w = 2*w2
    int rem = tid >> 5;
    int h   = rem & 63;
    int nc  = rem >> 6;

    int in_off = ((nc << 6) + h) * 64 + (w2 << 1);   // (nc*64 + h)*64 + 2*w2
    float2 xv = *reinterpret_cast<const float2*>(x + in_off);
    int2   wv = *reinterpret_cast<const int2*>(where + in_off);

    // Row 2h (sy=0): positions 0 (sx=0), 1 (sx=1)
    float4 r0;
    r0.x = (wv.x == 0) ? xv.x : 0.0f;
    r0.y = (wv.x == 1) ? xv.x : 0.0f;
    r0.z = (wv.y == 0) ? xv.y : 0.0f;
    r0.w = (wv.y == 1) ? xv.y : 0.0f;
    // Row 2h+1 (sy=1): positions 2, 3
    float4 r1;
    r1.x = (wv.x == 2) ? xv.x : 0.0f;
    r1.y = (wv.x == 3) ? xv.x : 0.0f;
    r1.z = (wv.y == 2) ? xv.y : 0.0f;
    r1.w = (wv.y == 3) ? xv.y : 0.0f;

    // Output: OH=128, OW=128. Base = (nc*128 + 2h)*128 + 4*w2. Max index
    // 2^25 so 32-bit arithmetic is safe.
    int out_off = (((nc << 7) + (h << 1)) << 7) + (w2 << 2);
    *reinterpret_cast<float4*>(out + out_off)       = r0;
    *reinterpret_cast<float4*>(out + out_off + 128) = r1;
}

extern "C" void kernel_launch(void* const* d_in, const int* in_sizes, int n_in,
                              void* d_out, int out_size, void* d_ws, size_t ws_size,
                              hipStream_t stream) {
    const float* x     = (const float*)d_in[0];
    const int*   where = (const int*)d_in[1];
    float*       out   = (float*)d_out;

    int n_elems = in_sizes[0];          // 32*64*64*64 = 8388608
    int n_pairs = n_elems >> 1;         // 4194304 threads
    int block = 256;
    int grid = (n_pairs + block - 1) / block;  // 16384 blocks

    WhatWhereUnPooling2D_51522427683437_kernel<<<grid, block, 0, stream>>>(
        x, where, out, n_pairs);
}